// Round 6
// baseline (538.872 us; speedup 1.0000x reference)
//
#include <hip/hip_runtime.h>

#define M_DIM 4096
#define K_DIM 4096
#define N_DIM 11008
#define BM 256
#define BN 128
#define BK 64    // bytes of K per tile iteration (int8)
#define NTILES (K_DIM / BK)   // 64

typedef int v4i  __attribute__((ext_vector_type(4)));
typedef int v16i __attribute__((ext_vector_type(16)));

// s_waitcnt immediates (gfx90a+ encoding: vmcnt[3:0]+[15:14], exp[6:4], lgkm[13:8])
#define WAIT_VM6 0x3F76   // vmcnt<=6  (one stage() = 6 loads still in flight)
#define WAIT_VM0 0x3F70   // vmcnt<=0

__device__ __forceinline__ void load_lds16(const void* g, void* l) {
    __builtin_amdgcn_global_load_lds(
        (const __attribute__((address_space(1))) void*)g,
        (__attribute__((address_space(3))) void*)l,
        16, 0, 0);
}

__device__ __forceinline__ unsigned int pack4(int4 v, int zp) {
    return ((unsigned int)(v.x - zp) & 0xFF)
         | (((unsigned int)(v.y - zp) & 0xFF) << 8)
         | (((unsigned int)(v.z - zp) & 0xFF) << 16)
         | (((unsigned int)(v.w - zp) & 0xFF) << 24);
}

// Fused pack: one launch covers x (with zero-point) then w (zp=0).
__global__ void pack_both_kernel(const int* __restrict__ x, const int* __restrict__ w,
                                 unsigned int* __restrict__ x8, unsigned int* __restrict__ w8,
                                 const int* __restrict__ zp_p, int nx16, int nw16) {
    int i = blockIdx.x * blockDim.x + threadIdx.x;
    if (i < nx16) {
        const int zp = zp_p[0];
        const int4* p = (const int4*)x + i * 4;
        uint4 o;
        o.x = pack4(p[0], zp);
        o.y = pack4(p[1], zp);
        o.z = pack4(p[2], zp);
        o.w = pack4(p[3], zp);
        ((uint4*)x8)[i] = o;
    } else {
        int j = i - nx16;
        if (j >= nw16) return;
        const int4* p = (const int4*)w + j * 4;
        uint4 o;
        o.x = pack4(p[0], 0);
        o.y = pack4(p[1], 0);
        o.z = pack4(p[2], 0);
        o.w = pack4(p[3], 0);
        ((uint4*)w8)[j] = o;
    }
}

// Config (R5 post-mortem):
//  - 2 blocks/CU co-residency (bubble absorption), acc[4][2]=128 AGPR +
//    ~108 VGPR <= 256/wave -> 2 waves/SIMD.
//  - Wave tile 128x64: 0.75 ds_reads/MFMA (best reachable at 256-reg cap).
//  - SQ_LDS_BANK_CONFLICT = 4 cyc/ds_read_b128 in EVERY layout tried
//    (R0/R3/R5) = m134's structural b128 overhead -> 1.69e7 is the floor;
//    stop chasing it.
//  - RING-3 buffers, ONE barrier per tile: stage(t+2) after barrier(t)
//    overwrites the buffer last read at t-1; every wave's t-1 reads were
//    consumed by its MFMAs before it reached barrier(t) -> safe without
//    the second barrier. Halves barrier count AND doubles prefetch
//    distance to ~2 tiles (~2900 cyc > 900 cyc HBM-miss latency).
//  - vmcnt counted (WAIT_VM6): 12 loads outstanding steady-state, current
//    tile's 6 guaranteed landed, next tile's 6 stay in flight.
//
// LDS swizzle (R4 fix, kept): granule g of row r at position g ^ ((r>>1)&3)
// in the 4-granule row (slot = r*4 + pos); same involution pre-applied to
// the global source granule so global_load_lds's linear dest receives
// swizzled data (both-sides-or-neither).
__global__ __launch_bounds__(256, 2) void gemm_i8_kernel(
    const signed char* __restrict__ A8,   // [M][K] int8 (x - zp)
    const signed char* __restrict__ B8,   // [N][K] int8 (w)
    const float* __restrict__ bias,
    const float* __restrict__ xs_p, const float* __restrict__ ws_p,
    const float* __restrict__ os_p, const int* __restrict__ ozp_p,
    int* __restrict__ out) {
    __shared__ v4i As0[BM * BK / 16];   // 16 KB each
    __shared__ v4i As1[BM * BK / 16];
    __shared__ v4i As2[BM * BK / 16];
    __shared__ v4i Bs0[BN * BK / 16];   // 8 KB each
    __shared__ v4i Bs1[BN * BK / 16];
    __shared__ v4i Bs2[BN * BK / 16];   // 72 KB total -> 2 blocks/CU (144 of 160 KB)

    const int tid  = threadIdx.x;
    const int lane = tid & 63;
    const int wave = tid >> 6;

    // ---- 2D XCD-aware swizzle: 1376 blocks = 8 XCD x 172 local.
    // Per XCD, 2x2 super-tiles (m pair x n pair) -> concurrent blocks share
    // both the A-panels and B-columns in that XCD's L2 (R5's 1-D n-major
    // order measured FETCH 382 MB vs R0's 2D 245 MB).
    const int bid   = blockIdx.x;
    const int xcd   = bid & 7;
    const int local = bid >> 3;                    // [0, 172)
    const int quad  = local >> 2;                  // [0, 43)
    const int idx   = local & 3;
    const int m_blk = xcd * 2 + (idx >> 1);        // [0, 16)
    const int n_blk = quad * 2 + (idx & 1);        // [0, 86)
    const int m0 = m_blk * BM;
    const int n0 = n_blk * BN;

    // ---- staging addresses: per thread 4 A granules + 2 B granules per tile ----
    long offA[4], offB[2];
    int  ldsA[4], ldsB[2];
#pragma unroll
    for (int j = 0; j < 4; ++j) {
        const int s   = tid + 256 * j;             // A slot [0,1024)
        const int row = s >> 2;
        const int gg  = (s & 3) ^ ((row >> 1) & 3); // pre-swizzled source granule
        offA[j] = (long)(m0 + row) * K_DIM + gg * 16;
        ldsA[j] = s;
    }
#pragma unroll
    for (int j = 0; j < 2; ++j) {
        const int s   = tid + 256 * j;             // B slot [0,512)
        const int row = s >> 2;
        const int gg  = (s & 3) ^ ((row >> 1) & 3);
        offB[j] = (long)(n0 + row) * K_DIM + gg * 16;
        ldsB[j] = s;
    }

    // ---- fragment slots for mfma_i32_32x32x32_i8 ----
    // A/B operand: m(or n) = lane&31, k bytes [(lane>>5)*16, +16)
    const int waveM = wave >> 1, waveN = wave & 1;
    const int l31 = lane & 31, h = lane >> 5;
    int aSlot[4][2], bSlot[2][2];
#pragma unroll
    for (int mt = 0; mt < 4; ++mt) {
        const int rA = waveM * 128 + mt * 32 + l31;
#pragma unroll
        for (int s = 0; s < 2; ++s) {
            const int g = 2 * s + h;
            aSlot[mt][s] = rA * 4 + (g ^ ((rA >> 1) & 3));
        }
    }
#pragma unroll
    for (int nt = 0; nt < 2; ++nt) {
        const int rB = waveN * 64 + nt * 32 + l31;
#pragma unroll
        for (int s = 0; s < 2; ++s) {
            const int g = 2 * s + h;
            bSlot[nt][s] = rB * 4 + (g ^ ((rB >> 1) & 3));
        }
    }

    v16i acc[4][2];
#pragma unroll
    for (int mt = 0; mt < 4; ++mt)
#pragma unroll
        for (int nt = 0; nt < 2; ++nt)
#pragma unroll
            for (int r = 0; r < 16; ++r) acc[mt][nt][r] = 0;

    // ---- helpers ----
    auto stage = [&](int tile, v4i* Asb, v4i* Bsb) {
        const long koff = (long)tile * BK;
#pragma unroll
        for (int j = 0; j < 4; ++j) load_lds16(A8 + offA[j] + koff, (char*)(Asb + ldsA[j]));
#pragma unroll
        for (int j = 0; j < 2; ++j) load_lds16(B8 + offB[j] + koff, (char*)(Bsb + ldsB[j]));
    };
    // No inner barriers (R0/R2-proven): 2-blocks/CU drift provides overlap.
    auto compute = [&](const v4i* Asb, const v4i* Bsb) {
#pragma unroll
        for (int s = 0; s < 2; ++s) {
            v4i a[4], b[2];
#pragma unroll
            for (int mt = 0; mt < 4; ++mt) a[mt] = Asb[aSlot[mt][s]];
#pragma unroll
            for (int nt = 0; nt < 2; ++nt) b[nt] = Bsb[bSlot[nt][s]];
#pragma unroll
            for (int mt = 0; mt < 4; ++mt)
#pragma unroll
                for (int nt = 0; nt < 2; ++nt)
                    acc[mt][nt] = __builtin_amdgcn_mfma_i32_32x32x32_i8(
                        a[mt], b[nt], acc[mt][nt], 0, 0, 0);
        }
    };

    // ---- ring-3 pipeline, one barrier per tile, counted vmcnt ----
    stage(0, As0, Bs0);          // 6 vm-ops in flight
    stage(1, As1, Bs1);          // 12 in flight

#pragma unroll 1
    for (int i = 0; i < 20; ++i) {
        const int t = 3 * i;     // tiles t, t+1, t+2 (buffers 0,1,2)
        __builtin_amdgcn_s_waitcnt(WAIT_VM6);   // tile t landed; t+1 flying
        __builtin_amdgcn_s_barrier();
        stage(t + 2, As2, Bs2);                 // overwrites buf read at t-1: safe
        compute(As0, Bs0);
        __builtin_amdgcn_s_waitcnt(WAIT_VM6);
        __builtin_amdgcn_s_barrier();
        stage(t + 3, As0, Bs0);
        compute(As1, Bs1);
        __builtin_amdgcn_s_waitcnt(WAIT_VM6);
        __builtin_amdgcn_s_barrier();
        stage(t + 4, As1, Bs1);
        compute(As2, Bs2);
    }
    // peeled tail: tiles 60..63 (stages 62, 63 remain)
    __builtin_amdgcn_s_waitcnt(WAIT_VM6);       // t=60 (buf0)
    __builtin_amdgcn_s_barrier();
    stage(62, As2, Bs2);
    compute(As0, Bs0);
    __builtin_amdgcn_s_waitcnt(WAIT_VM6);       // t=61 (buf1)
    __builtin_amdgcn_s_barrier();
    stage(63, As0, Bs0);
    compute(As1, Bs1);
    __builtin_amdgcn_s_waitcnt(WAIT_VM6);       // t=62 (buf2)
    __builtin_amdgcn_s_barrier();
    compute(As2, Bs2);
    __builtin_amdgcn_s_waitcnt(WAIT_VM0);       // t=63 (buf0)
    __builtin_amdgcn_s_barrier();
    compute(As0, Bs0);

    // ---- epilogue: dequant + bias, requant to [0,255] ----
    // C/D 32x32: col = lane&31, row = (reg&3) + 8*(reg>>2) + 4*(lane>>5)
    const float scale  = xs_p[0] * ws_p[0];
    const float inv_os = 1.0f / os_p[0];
    const int   ozp    = ozp_p[0];
#pragma unroll
    for (int mt = 0; mt < 4; ++mt) {
        const int rbase = m0 + waveM * 128 + mt * 32 + 4 * h;
#pragma unroll
        for (int nt = 0; nt < 2; ++nt) {
            const int col = n0 + waveN * 64 + nt * 32 + l31;
            const float bv = bias[col];
#pragma unroll
            for (int r = 0; r < 16; ++r) {
                const int row = rbase + (r & 3) + 8 * (r >> 2);
                float y = (float)acc[mt][nt][r] * scale + bv;
                int q = (int)rintf(y * inv_os) + ozp;
                q = q < 0 ? 0 : (q > 255 ? 255 : q);
                out[(long)row * N_DIM + col] = q;
            }
        }
    }
}

extern "C" void kernel_launch(void* const* d_in, const int* in_sizes, int n_in,
                              void* d_out, int out_size, void* d_ws, size_t ws_size,
                              hipStream_t stream) {
    const int*   x_q  = (const int*)d_in[0];
    const int*   w_q  = (const int*)d_in[1];
    const float* bias = (const float*)d_in[2];
    const float* xs   = (const float*)d_in[3];
    const float* wsc  = (const float*)d_in[4];
    const float* os   = (const float*)d_in[5];
    const int*   xzp  = (const int*)d_in[6];
    const int*   ozp  = (const int*)d_in[7];

    signed char* x8 = (signed char*)d_ws;                               // 16 MB
    signed char* w8 = (signed char*)d_ws + (size_t)M_DIM * K_DIM;       // 45 MB

    const int nx16 = M_DIM * K_DIM / 16;
    const int nw16 = N_DIM * K_DIM / 16;
    const int npack = nx16 + nw16;
    pack_both_kernel<<<(npack + 255) / 256, 256, 0, stream>>>(
        x_q, w_q, (unsigned int*)x8, (unsigned int*)w8, xzp, nx16, nw16);

    const int nblocks = (M_DIM / BM) * (N_DIM / BN);   // 16 * 86 = 1376
    gemm_i8_kernel<<<nblocks, 256, 0, stream>>>(x8, w8, bias, xs, wsc, os, ozp, (int*)d_out);
}